// Round 4
// baseline (146.757 us; speedup 1.0000x reference)
//
#include <hip/hip_runtime.h>

#define L_SIG 65536
#define NBATCH 16
#define M_BLK 1024            // positions per block
#define SCOPY 1288            // halfs per shifted signal copy (1280 data + 8 pad)

typedef _Float16 half8 __attribute__((ext_vector_type(8)));
typedef float f32x16 __attribute__((ext_vector_type(16)));

// ---------------------------------------------------------------------------
// CWT real part via MFMA:
//   out[(n*32+s)*65536 + h] = sum_k sig[n][h+k-128] * w[s][k]
//   w[s][k] = exp(-0.5 t^2) * cos(2*pi*6*t/scale), t=(k-128)/scale, scale=1+s
//
// Block: 256 thr (4 waves), one batch n, 1024 positions, all 32 scales.
// GEMM view: M=32 (scales), N=positions, K=256 (taps), A = wavelet (hoisted
// to 16 register frags), B = signal from LDS. mfma_f32_32x32x16_f16:
//   D col = lane&31 = POSITION (contiguous), row = scale
//       = (reg&3)+8*(reg>>2)+4*(lane>>5)
// => accumulators store DIRECTLY to global as 2x128B coalesced segments
// (R2: deleted the whole LDS-transpose epilogue, -10.6us, matching its
// LDS-op cycle count -> kernel behaves LDS/issue-serialized).
//
// R3 changes (resubmitted verbatim in R4 — prior bench was an infra failure,
// "MI355X container failed twice"; kernel never measured):
//  1. B-ring: tile1's B-frag at k-step ks IS tile0's at ks+2 (positions +32
//     = 2 k-steps of 16). Ring of 4 b-regs: reads/chunk 32 -> 18 b128
//     (inner LDS reads -39%, the dominant non-HBM pipe term).
//  2. #pragma unroll 2 on chunk loop: overlap store tail with next chunk's
//     ds_reads/MFMAs (no barriers in the loop, only register deps).
//  3. Interior blocks (h0>=128 && h0+1152<=L_SIG; 62 of 64) skip per-element
//     bounds checks in staging (-80 VALU/thread).
//
// LDS: w_lds[32][256] fp16 (16B chunks XOR-swizzled by scale&7) +
// s_lds = 8 shifted copies of signal tile (copy c shifted by c) so every
// B-read is a 16B-aligned ds_read_b128 (copy = pos&7). Total 36,992 B.
// ---------------------------------------------------------------------------
__global__ __launch_bounds__(256, 3) void cwt_mfma(
        const float* __restrict__ sig,
        float* __restrict__ out) {

    __shared__ __align__(16) _Float16 w_lds[32 * 256];   // 16384 B
    __shared__ __align__(16) _Float16 s_lds[8 * SCOPY];  // 20608 B

    const int tid = threadIdx.x;
    const int n   = blockIdx.y;
    const int h0  = blockIdx.x * M_BLK;

    // ---- generate wavelet bank into w_lds (fp16, chunk-swizzled) ----
    {
        int o  = tid >> 3;                 // scale 0..31
        int k0 = (tid & 7) * 32;           // 32 taps per thread
        float scale = 1.0f + (float)o;
        float inv_s = 1.0f / scale;
        float pcoef = 37.699111843077518861f * inv_s * inv_s; // 2*pi*6/scale^2
        #pragma unroll
        for (int cc = 0; cc < 4; ++cc) {
            union { _Float16 h[8]; uint4 u4; } pk;
            #pragma unroll
            for (int j = 0; j < 8; ++j) {
                float km = (float)(k0 + cc * 8 + j) - 128.0f;
                float t = km * inv_s;
                float env = __expf(-0.5f * t * t);
                pk.h[j] = (_Float16)(env * __cosf(pcoef * km));
            }
            int cidx = (k0 >> 3) + cc;     // logical 16B chunk 0..31
            *(uint4*)&w_lds[o * 256 + ((cidx ^ (o & 7)) << 3)] = pk.u4;
        }
    }

    // ---- stage 8 shifted fp16 copies of signal tile [h0-128, h0+1152) ----
    {
        const float* sp = sig + (size_t)n * L_SIG;
        const int base = h0 - 128;
        if (h0 >= 128 && h0 + 1152 <= L_SIG) {
            // interior: no bounds checks
            #pragma unroll
            for (int c = 0; c < 8; ++c) {
                for (int xi = tid; xi < 640; xi += 256) {
                    int x = xi * 2;
                    int e = base + c + x;
                    union { _Float16 h[2]; unsigned u; } p;
                    p.h[0] = (_Float16)sp[e];
                    p.h[1] = (_Float16)sp[e + 1];
                    *(unsigned*)&s_lds[c * SCOPY + x] = p.u;
                }
            }
        } else {
            #pragma unroll
            for (int c = 0; c < 8; ++c) {
                for (int xi = tid; xi < 640; xi += 256) {
                    int x = xi * 2;
                    int e = base + c + x;
                    float v0 = ((unsigned)e       < L_SIG) ? sp[e]     : 0.0f;
                    float v1 = ((unsigned)(e + 1) < L_SIG) ? sp[e + 1] : 0.0f;
                    union { _Float16 h[2]; unsigned u; } p;
                    p.h[0] = (_Float16)v0;
                    p.h[1] = (_Float16)v1;
                    *(unsigned*)&s_lds[c * SCOPY + x] = p.u;
                }
            }
        }
    }
    __syncthreads();

    const int w  = tid >> 6;
    const int l  = tid & 63;
    const int m5 = l & 31;     // A row (scale) / B col (position) / D col
    const int hk = l >> 5;     // k-half selector

    // ---- hoist all 16 wavelet A-fragments to registers ----
    half8 af[16];
    #pragma unroll
    for (int ks = 0; ks < 16; ++ks) {
        int cidx = (ks << 1) + hk;
        af[ks] = *(const half8*)&w_lds[m5 * 256 + ((cidx ^ (m5 & 7)) << 3)];
    }

    // B-read base: copy (m5&7), x = w*64 + (m5&24) + hk*8 (+ c*256 + ks*16).
    // All terms multiple of 8 halfs -> aligned ds_read_b128.
    const int bbase = (m5 & 7) * SCOPY + (m5 & 24) + (hk << 3) + w * 64;
    const size_t obase = ((size_t)(n * 32) << 16) + (size_t)(h0 + w * 64);

    // Ring invariant: b[j] holds tile0 B-frag for k-step k == j (mod 4);
    // loaded at iteration k-4, consumed by acc0 at k and acc1 at k-2
    // (tile1 frag at ks == tile0 frag at ks+2: positions +32 = +2 k-steps).
    #pragma unroll 2
    for (int c = 0; c < 4; ++c) {
        const _Float16* bp = &s_lds[bbase + c * 256];
        f32x16 acc0 = {};
        f32x16 acc1 = {};
        half8 b[4];
        #pragma unroll
        for (int u = 0; u < 4; ++u)
            b[u] = *(const half8*)&bp[u * 16];

        #pragma unroll
        for (int ks = 0; ks < 16; ++ks) {
            acc0 = __builtin_amdgcn_mfma_f32_32x32x16_f16(af[ks], b[ks & 3],
                                                          acc0, 0, 0, 0);
            acc1 = __builtin_amdgcn_mfma_f32_32x32x16_f16(af[ks], b[(ks + 2) & 3],
                                                          acc1, 0, 0, 0);
            if (ks < 14)
                b[ks & 3] = *(const half8*)&bp[(ks + 4) * 16];  // k-step ks+4
        }

        // ---- direct coalesced stores from accumulators ----
        // reg r -> scale row (r&3)+8*(r>>2)+4*hk, lanes m5 -> 32 contiguous
        // positions: each store = 2 x 128B segments (hk=0: row, hk=1: row+4).
        const size_t ob = obase + (size_t)(c * 256);
        #pragma unroll
        for (int r = 0; r < 16; ++r) {
            size_t po = ob + ((size_t)((r & 3) + ((r >> 2) << 3) + (hk << 2)) << 16);
            out[po + m5]      = acc0[r];
            out[po + 32 + m5] = acc1[r];
        }
    }
}

extern "C" void kernel_launch(void* const* d_in, const int* in_sizes, int n_in,
                              void* d_out, int out_size, void* d_ws, size_t ws_size,
                              hipStream_t stream) {
    const float* sig = (const float*)d_in[0];
    float* out = (float*)d_out;
    cwt_mfma<<<dim3(L_SIG / M_BLK, NBATCH), dim3(256), 0, stream>>>(sig, out);
}

// Round 5
// 146.027 us; speedup vs baseline: 1.0050x; 1.0050x over previous
//
#include <hip/hip_runtime.h>

#define L_SIG 65536
#define NBATCH 16
#define M_BLK 1024            // positions per block
#define SCOPY 1288            // halfs per shifted signal copy (1280 data + 8 pad)

typedef _Float16 half8 __attribute__((ext_vector_type(8)));
typedef float f32x16 __attribute__((ext_vector_type(16)));
typedef float f32x4  __attribute__((ext_vector_type(4)));

// ---------------------------------------------------------------------------
// CWT real part via MFMA:
//   out[(n*32+s)*65536 + h] = sum_k sig[n][h+k-128] * w[s][k]
//   w[s][k] = exp(-0.5 t^2) * cos(2*pi*6*t/scale), t=(k-128)/scale, scale=1+s
//
// Block: 256 thr (4 waves), one batch n, 1024 positions, all 32 scales.
// GEMM view: M=32 (scales), N=positions, K=256 (taps), A = wavelet (hoisted
// to 16 register frags), B = signal from LDS. mfma_f32_32x32x16_f16:
//   D col = lane&31 = POSITION, row = scale = (reg&3)+8*(reg>>2)+4*(lane>>5)
//
// R5 theory: kernel ~62us vs issue-model ~7us and HBM floor ~21us; R1
// (occupancy) and R3 (LDS reads) both null -> bottleneck = HBM WRITE
// efficiency (~2.3 TB/s vs fill's 6.7 on same buffer). Direct stores emit
// 128-256B islands scattered over 32 planes x 256KB stride from every wave.
// Fix: block-level plane-major epilogue. w_lds is DEAD after af-hoist ->
// reuse as ep[32 planes][128 pos] f32 (exactly 16384 B). Per chunk, 2
// passes: waves 0-1 stage acc (pos 0-127), barrier, ALL waves store
// float4-per-thread (each inst = 512B contiguous per plane, block sweeps
// planes monotonically, barrier-synced); then waves 2-3 stage pos 128-255.
// LDS: stage writes bank p&31 distinct / lane-pairs 2-way (free); reads
// consecutive-dword b128 conflict-free. 4 barriers/chunk.
//
// s_lds: 8 shifted fp16 copies of signal tile (copy c shifted by c) so every
// B-read is 16B-aligned ds_read_b128 (copy = pos&7). B-ring: tile1 frag at
// k-step ks == tile0 frag at ks+2 (pos+32 = 2 k-steps) -> ring of 4, 18
// reads/chunk. LDS total 36,992 B -> 4 blocks/CU.
// ---------------------------------------------------------------------------
__global__ __launch_bounds__(256, 3) void cwt_mfma(
        const float* __restrict__ sig,
        float* __restrict__ out) {

    __shared__ __align__(16) _Float16 w_lds[32 * 256];   // 16384 B (-> ep)
    __shared__ __align__(16) _Float16 s_lds[8 * SCOPY];  // 20608 B

    const int tid = threadIdx.x;
    const int n   = blockIdx.y;
    const int h0  = blockIdx.x * M_BLK;

    // ---- generate wavelet bank into w_lds (fp16, chunk-swizzled) ----
    {
        int o  = tid >> 3;                 // scale 0..31
        int k0 = (tid & 7) * 32;           // 32 taps per thread
        float scale = 1.0f + (float)o;
        float inv_s = 1.0f / scale;
        float pcoef = 37.699111843077518861f * inv_s * inv_s; // 2*pi*6/scale^2
        #pragma unroll
        for (int cc = 0; cc < 4; ++cc) {
            union { _Float16 h[8]; uint4 u4; } pk;
            #pragma unroll
            for (int j = 0; j < 8; ++j) {
                float km = (float)(k0 + cc * 8 + j) - 128.0f;
                float t = km * inv_s;
                float env = __expf(-0.5f * t * t);
                pk.h[j] = (_Float16)(env * __cosf(pcoef * km));
            }
            int cidx = (k0 >> 3) + cc;     // logical 16B chunk 0..31
            *(uint4*)&w_lds[o * 256 + ((cidx ^ (o & 7)) << 3)] = pk.u4;
        }
    }

    // ---- stage 8 shifted fp16 copies of signal tile [h0-128, h0+1152) ----
    {
        const float* sp = sig + (size_t)n * L_SIG;
        const int base = h0 - 128;
        if (h0 >= 128 && h0 + 1152 <= L_SIG) {
            #pragma unroll
            for (int c = 0; c < 8; ++c) {
                for (int xi = tid; xi < 640; xi += 256) {
                    int x = xi * 2;
                    int e = base + c + x;
                    union { _Float16 h[2]; unsigned u; } p;
                    p.h[0] = (_Float16)sp[e];
                    p.h[1] = (_Float16)sp[e + 1];
                    *(unsigned*)&s_lds[c * SCOPY + x] = p.u;
                }
            }
        } else {
            #pragma unroll
            for (int c = 0; c < 8; ++c) {
                for (int xi = tid; xi < 640; xi += 256) {
                    int x = xi * 2;
                    int e = base + c + x;
                    float v0 = ((unsigned)e       < L_SIG) ? sp[e]     : 0.0f;
                    float v1 = ((unsigned)(e + 1) < L_SIG) ? sp[e + 1] : 0.0f;
                    union { _Float16 h[2]; unsigned u; } p;
                    p.h[0] = (_Float16)v0;
                    p.h[1] = (_Float16)v1;
                    *(unsigned*)&s_lds[c * SCOPY + x] = p.u;
                }
            }
        }
    }
    __syncthreads();

    const int w  = tid >> 6;
    const int l  = tid & 63;
    const int m5 = l & 31;     // A row (scale) / B col (position) / D col
    const int hk = l >> 5;     // k-half selector

    // ---- hoist all 16 wavelet A-fragments to registers ----
    half8 af[16];
    #pragma unroll
    for (int ks = 0; ks < 16; ++ks) {
        int cidx = (ks << 1) + hk;
        af[ks] = *(const half8*)&w_lds[m5 * 256 + ((cidx ^ (m5 & 7)) << 3)];
    }
    // w_lds is dead from here; reused as ep[plane 0..31][pos 0..127] f32.
    float* ep = (float*)w_lds;

    // B-read base: copy (m5&7), x = w*64 + (m5&24) + hk*8 (+ c*256 + ks*16).
    const int bbase = (m5 & 7) * SCOPY + (m5 & 24) + (hk << 3) + w * 64;
    const size_t nsbase = ((size_t)(n * 32) << 16);

    #pragma unroll 1
    for (int c = 0; c < 4; ++c) {
        const _Float16* bp = &s_lds[bbase + c * 256];
        f32x16 acc0 = {};
        f32x16 acc1 = {};
        half8 b[4];
        #pragma unroll
        for (int u = 0; u < 4; ++u)
            b[u] = *(const half8*)&bp[u * 16];

        #pragma unroll
        for (int ks = 0; ks < 16; ++ks) {
            acc0 = __builtin_amdgcn_mfma_f32_32x32x16_f16(af[ks], b[ks & 3],
                                                          acc0, 0, 0, 0);
            acc1 = __builtin_amdgcn_mfma_f32_32x32x16_f16(af[ks], b[(ks + 2) & 3],
                                                          acc1, 0, 0, 0);
            if (ks < 14)
                b[ks & 3] = *(const half8*)&bp[(ks + 4) * 16];  // k-step ks+4
        }

        // ---- plane-major epilogue: 2 passes through ep (16 KB) ----
        // pass P: waves 2P..2P+1 stage their 128 positions; all waves store.
        #pragma unroll
        for (int P = 0; P < 2; ++P) {
            __syncthreads();                 // ep free (prev reads done)
            if ((w >> 1) == P) {
                // wave covers global pos w*64..w*64+63 -> ep p = (w&1)*64+..
                int p = ((w & 1) << 6) + m5;
                #pragma unroll
                for (int r = 0; r < 16; ++r) {
                    int row = (r & 3) + ((r >> 2) << 3) + (hk << 2);
                    ep[row * 128 + p]      = acc0[r];
                    ep[row * 128 + p + 32] = acc1[r];
                }
            }
            __syncthreads();                 // staging visible to all
            // store 32 planes x 128 pos: thread t handles float4 f=i*256+t:
            // plane = f>>5, q4 = (f&31)*4. Each wave-inst = 2 planes x 512B
            // contiguous; block sweeps planes 8i..8i+7 together.
            const int hbase = c * 256 + (P << 7);
            #pragma unroll
            for (int i = 0; i < 4; ++i) {
                int f = i * 256 + tid;
                int plane = f >> 5;
                int q4 = (f & 31) << 2;
                f32x4 v = *(const f32x4*)&ep[plane * 128 + q4];
                *(f32x4*)&out[nsbase + ((size_t)plane << 16)
                              + (size_t)(h0 + hbase + q4)] = v;
            }
        }
    }
}

extern "C" void kernel_launch(void* const* d_in, const int* in_sizes, int n_in,
                              void* d_out, int out_size, void* d_ws, size_t ws_size,
                              hipStream_t stream) {
    const float* sig = (const float*)d_in[0];
    float* out = (float*)d_out;
    cwt_mfma<<<dim3(L_SIG / M_BLK, NBATCH), dim3(256), 0, stream>>>(sig, out);
}